// Round 1
// baseline (171.882 us; speedup 1.0000x reference)
//
#include <hip/hip_runtime.h>
#include <math.h>

// Problem constants
#define NB   2048     // batch
#define ND   1024     // dim
#define INV_TEMP 10.0f
#define LAMBDA_CS 0.5f

using short8  = __attribute__((ext_vector_type(8))) short;
using floatx4 = __attribute__((ext_vector_type(4))) float;

__device__ __forceinline__ ushort f32_to_bf16_rne(float f) {
  union { float f; unsigned u; } v; v.f = f;
  unsigned u = v.u;
  u += 0x7FFFu + ((u >> 16) & 1u);   // round-to-nearest-even
  return (ushort)(u >> 16);
}

// ---------------------------------------------------------------------------
// Kernel 1: fused row L2-normalize (-> bf16 M, t-order {e,k,et,kt}) + cs-reg
// partial per row. One block per row b; each thread holds one float4 per mat.
// ---------------------------------------------------------------------------
__global__ __launch_bounds__(256) void k_norm_reg(
    const float* __restrict__ e, const float* __restrict__ k,
    const float* __restrict__ et, const float* __restrict__ kt,
    const float* __restrict__ ratios,
    ushort* __restrict__ M, float* __restrict__ reg_partial)
{
  const int b = blockIdx.x, tid = threadIdx.x;
  const int wave = tid >> 6, lane = tid & 63;

  float4 ve  = ((const float4*)(e  + (size_t)b * ND))[tid];
  float4 vk  = ((const float4*)(k  + (size_t)b * ND))[tid];
  float4 vet = ((const float4*)(et + (size_t)b * ND))[tid];
  float4 vkt = ((const float4*)(kt + (size_t)b * ND))[tid];

  float s0 = ve.x*ve.x + ve.y*ve.y + ve.z*ve.z + ve.w*ve.w;
  float s1 = vk.x*vk.x + vk.y*vk.y + vk.z*vk.z + vk.w*vk.w;
  float s2 = vet.x*vet.x + vet.y*vet.y + vet.z*vet.z + vet.w*vet.w;
  float s3 = vkt.x*vkt.x + vkt.y*vkt.y + vkt.z*vkt.z + vkt.w*vkt.w;
  #pragma unroll
  for (int o = 1; o < 64; o <<= 1) {
    s0 += __shfl_xor(s0, o); s1 += __shfl_xor(s1, o);
    s2 += __shfl_xor(s2, o); s3 += __shfl_xor(s3, o);
  }
  __shared__ float red[4][4];
  if (lane == 0) { red[wave][0] = s0; red[wave][1] = s1; red[wave][2] = s2; red[wave][3] = s3; }
  __syncthreads();
  const float ie  = 1.0f / sqrtf(red[0][0] + red[1][0] + red[2][0] + red[3][0]);
  const float ik  = 1.0f / sqrtf(red[0][1] + red[1][1] + red[2][1] + red[3][1]);
  const float iet = 1.0f / sqrtf(red[0][2] + red[1][2] + red[2][2] + red[3][2]);
  const float ikt = 1.0f / sqrtf(red[0][3] + red[1][3] + red[2][3] + red[3][3]);

  // write normalized bf16 rows, t order {0:e, 1:k, 2:et, 3:kt}
  {
    ushort o4[4];
    o4[0] = f32_to_bf16_rne(ve.x * ie);  o4[1] = f32_to_bf16_rne(ve.y * ie);
    o4[2] = f32_to_bf16_rne(ve.z * ie);  o4[3] = f32_to_bf16_rne(ve.w * ie);
    *(ushort4*)(M + ((size_t)0 * NB + b) * ND + tid * 4) = *(ushort4*)o4;
    o4[0] = f32_to_bf16_rne(vk.x * ik);  o4[1] = f32_to_bf16_rne(vk.y * ik);
    o4[2] = f32_to_bf16_rne(vk.z * ik);  o4[3] = f32_to_bf16_rne(vk.w * ik);
    *(ushort4*)(M + ((size_t)1 * NB + b) * ND + tid * 4) = *(ushort4*)o4;
    o4[0] = f32_to_bf16_rne(vet.x * iet); o4[1] = f32_to_bf16_rne(vet.y * iet);
    o4[2] = f32_to_bf16_rne(vet.z * iet); o4[3] = f32_to_bf16_rne(vet.w * iet);
    *(ushort4*)(M + ((size_t)2 * NB + b) * ND + tid * 4) = *(ushort4*)o4;
    o4[0] = f32_to_bf16_rne(vkt.x * ikt); o4[1] = f32_to_bf16_rne(vkt.y * ikt);
    o4[2] = f32_to_bf16_rne(vkt.z * ikt); o4[3] = f32_to_bf16_rne(vkt.w * ikt);
    *(ushort4*)(M + ((size_t)3 * NB + b) * ND + tid * 4) = *(ushort4*)o4;
  }

  // cs-reg partial
  const float r = ratios[b], rm = 1.0f - r;
  float a1 = 0.f, a2 = 0.f;
  {
    float en, kn, d1, d2;
    en = ve.x*ie; kn = vk.x*ik;
    d1 = vet.x*iet - (r*en + rm*kn); d2 = vkt.x*ikt - (rm*en + r*kn);
    a1 += d1*d1; a2 += d2*d2;
    en = ve.y*ie; kn = vk.y*ik;
    d1 = vet.y*iet - (r*en + rm*kn); d2 = vkt.y*ikt - (rm*en + r*kn);
    a1 += d1*d1; a2 += d2*d2;
    en = ve.z*ie; kn = vk.z*ik;
    d1 = vet.z*iet - (r*en + rm*kn); d2 = vkt.z*ikt - (rm*en + r*kn);
    a1 += d1*d1; a2 += d2*d2;
    en = ve.w*ie; kn = vk.w*ik;
    d1 = vet.w*iet - (r*en + rm*kn); d2 = vkt.w*ikt - (rm*en + r*kn);
    a1 += d1*d1; a2 += d2*d2;
  }
  #pragma unroll
  for (int o = 1; o < 64; o <<= 1) { a1 += __shfl_xor(a1, o); a2 += __shfl_xor(a2, o); }
  __shared__ float red2[4][2];
  if (lane == 0) { red2[wave][0] = a1; red2[wave][1] = a2; }
  __syncthreads();
  if (tid == 0) {
    float t1 = red2[0][0] + red2[1][0] + red2[2][0] + red2[3][0];
    float t2 = red2[0][1] + red2[1][1] + red2[2][1] + red2[3][1];
    reg_partial[b] = sqrtf(t1) + sqrtf(t2);
  }
}

// ---------------------------------------------------------------------------
// Kernel 2: 256x256-tile, BK=64, 8-wave, 8-phase counted-vmcnt GEMM
// (T2 swizzle + T3/T4 schedule + T5 setprio), fused exp + row-sum partials +
// diagonal capture + symmetric column-sum mirror.
//   Grid: 392 = 256 (right half: by 0..15, bx 16..31) + 136 (upper triangle
//   incl diagonal of left 4096x4096 half: bx in [by,16)).
//   rsp layout: [slot 0..31][row 0..4095]. Row-block by: direct slots
//   [by,32), mirrored col-sums provide slots [0,by). No atomics.
//
// LDS: As/Bs double-buffered 256x64 bf16 each = 128 KiB. Logical element
// (row, colByte cb) lives at physical cb ^ ((row&7)<<4); global_load_lds
// writes linearly (wave-uniform base + lane*16) so the swizzle is applied
// to the per-lane GLOBAL source address (rule #21), and re-applied on
// every ds_read address. ds_read_b128 is then max 2-way (free).
//
// Phase schedule (tiles t=2i in buf0, t=2i+1 in buf1), per iteration:
//   ph1 (mq0,kk0,+B)  stage A(2i+1) h0 -> As[1]
//   ph2 (mq0,kk1,+B)  stage A(2i+1) h1 -> As[1]
//   ph3 (mq1,kk0)     stage B(2i+2) h0 -> Bs[0]   (Bs[0] last read ph2)
//   ph4 (mq1,kk1)     stage B(2i+2) h1 -> Bs[0]   + s_waitcnt vmcnt(4)
//   ph5 (mq0,kk0,+B)  stage A(2i+2) h0 -> As[0]   (As[0] last read ph4)
//   ph6 (mq0,kk1,+B)  stage A(2i+2) h1 -> As[0]
//   ph7 (mq1,kk0)     stage B(2i+3) h0 -> Bs[1]   (Bs[1] B last read ph6)
//   ph8 (mq1,kk1)     stage B(2i+3) h1 -> Bs[1]   + s_waitcnt vmcnt(4)
// vmcnt(4) leaves exactly the 2 most recent half-tiles in flight; everything
// the next 4 phases read has landed. Stages never target a slot read in the
// same or a later phase before the next overwrite (verified slot-by-slot).
// ---------------------------------------------------------------------------

#define STAGE_A(TT, HH, BUF) do {                                              \
  _Pragma("unroll")                                                            \
  for (int L_ = 0; L_ < 2; ++L_) {                                             \
    const int u_ = L_ * 512 + tid;                                             \
    const int rr_ = u_ >> 3;                                                   \
    const int sc_ = ((u_ & 7) * 16) ^ ((rr_ & 7) << 4);                        \
    const ushort* gp_ = M + (size_t)(i0 + (HH)*128 + rr_) * ND + (TT)*64 + (sc_ >> 1); \
    __builtin_amdgcn_global_load_lds(                                          \
        (const __attribute__((address_space(1))) unsigned int*)gp_,            \
        (__attribute__((address_space(3))) unsigned int*)&As[BUF][(HH)*8192 + L_*4096 + wave*512], \
        16, 0, 0);                                                             \
  }                                                                            \
} while (0)

#define STAGE_B(TT, HH, BUF) do {                                              \
  _Pragma("unroll")                                                            \
  for (int L_ = 0; L_ < 2; ++L_) {                                             \
    const int u_ = L_ * 512 + tid;                                             \
    const int rr_ = u_ >> 3;                                                   \
    const int sc_ = ((u_ & 7) * 16) ^ ((rr_ & 7) << 4);                        \
    const ushort* gp_ = M + (size_t)(j0 + (HH)*128 + rr_) * ND + (TT)*64 + (sc_ >> 1); \
    __builtin_amdgcn_global_load_lds(                                          \
        (const __attribute__((address_space(1))) unsigned int*)gp_,            \
        (__attribute__((address_space(3))) unsigned int*)&Bs[BUF][(HH)*8192 + L_*4096 + wave*512], \
        16, 0, 0);                                                             \
  }                                                                            \
} while (0)

#define PHASE(BUF, MQ, KK, LOADB, WAIT, STMT) do {                             \
  short8 af_[4];                                                               \
  _Pragma("unroll")                                                            \
  for (int mi_ = 0; mi_ < 4; ++mi_) {                                          \
    const int row_ = wrow + ((MQ)*4 + mi_)*16 + m;                             \
    const int cb_ = ((KK)*64 + q*16) ^ ((row_ & 7) << 4);                      \
    af_[mi_] = *(const short8*)&As[BUF][row_*64 + (cb_ >> 1)];                 \
  }                                                                            \
  if (LOADB) {                                                                 \
    _Pragma("unroll")                                                          \
    for (int ni_ = 0; ni_ < 4; ++ni_) {                                        \
      const int rb_ = wcol + ni_*16 + m;                                       \
      const int cb_ = ((KK)*64 + q*16) ^ ((rb_ & 7) << 4);                     \
      bfr[KK][ni_] = *(const short8*)&Bs[BUF][rb_*64 + (cb_ >> 1)];            \
    }                                                                          \
  }                                                                            \
  STMT;                                                                        \
  __builtin_amdgcn_s_barrier();                                                \
  asm volatile("s_waitcnt lgkmcnt(0)" ::: "memory");                           \
  __builtin_amdgcn_s_setprio(1);                                               \
  _Pragma("unroll")                                                            \
  for (int mi_ = 0; mi_ < 4; ++mi_)                                            \
    _Pragma("unroll")                                                          \
    for (int ni_ = 0; ni_ < 4; ++ni_)                                          \
      acc[(MQ)*4 + mi_][ni_] = __builtin_amdgcn_mfma_f32_16x16x32_bf16(        \
          af_[mi_], bfr[KK][ni_], acc[(MQ)*4 + mi_][ni_], 0, 0, 0);            \
  __builtin_amdgcn_s_setprio(0);                                               \
  if (WAIT) asm volatile("s_waitcnt vmcnt(4)" ::: "memory");                   \
  __builtin_amdgcn_s_barrier();                                                \
} while (0)

__global__ __launch_bounds__(512, 2) void k_gemm_exp_rowsum(
    const ushort* __restrict__ M,
    float* __restrict__ rsp,      // [32][4096] partials
    float* __restrict__ diag)     // [2][4][2048]  (side, t, n); slot 4 unused
{
  __shared__ __align__(16) ushort As[2][16384];
  __shared__ __align__(16) ushort Bs[2][16384];

  int bx, by;
  {
    int idx = blockIdx.x;
    if (idx < 256) { by = idx >> 4; bx = 16 + (idx & 15); }
    else {
      int t = idx - 256; by = 0;
      while (t >= 16 - by) { t -= 16 - by; ++by; }
      bx = by + t;
    }
  }
  const bool sym = (bx < 16) && (bx > by);
  const int i0 = by * 256;
  const int j0 = bx * 256;

  const int tid  = threadIdx.x;
  const int wave = tid >> 6;
  const int lane = tid & 63;
  const int q = lane >> 4;       // quad 0..3
  const int m = lane & 15;       // spatial index within 16
  const int wr = wave >> 2;      // 0..1
  const int wc = wave & 3;       // 0..3
  const int wrow = wr * 128;
  const int wcol = wc * 64;

  floatx4 acc[8][4] = {};
  short8 bfr[2][4];

  // prologue: A(0), B(0), B(1); leave B(1) (4 loads) in flight
  STAGE_A(0, 0, 0); STAGE_A(0, 1, 0);
  STAGE_B(0, 0, 0); STAGE_B(0, 1, 0);
  STAGE_B(1, 0, 1); STAGE_B(1, 1, 1);
  asm volatile("s_waitcnt vmcnt(4)" ::: "memory");
  __builtin_amdgcn_s_barrier();

  #pragma unroll 1
  for (int i = 0; i < 8; ++i) {
    const int t1 = 2*i + 1;
    const int t2 = (2*i + 2) & 15;   // last iter wraps: harmless re-fetch,
    const int t3 = (2*i + 3) & 15;   // drained by __syncthreads below
    PHASE(0, 0, 0, 1, 0, STAGE_A(t1, 0, 1));
    PHASE(0, 0, 1, 1, 0, STAGE_A(t1, 1, 1));
    PHASE(0, 1, 0, 0, 0, STAGE_B(t2, 0, 0));
    PHASE(0, 1, 1, 0, 1, STAGE_B(t2, 1, 0));
    PHASE(1, 0, 0, 1, 0, STAGE_A(t2, 0, 0));
    PHASE(1, 0, 1, 1, 0, STAGE_A(t2, 1, 0));
    PHASE(1, 1, 0, 0, 0, STAGE_B(t3, 0, 1));
    PHASE(1, 1, 1, 0, 1, STAGE_B(t3, 1, 1));
  }

  __syncthreads();   // full vmcnt/lgkmcnt drain + barrier before LDS overlay

  // Epilogue. C/D layout: col = lane&15, row = q*4 + reg  [m89/m91]
  float* redR = (float*)&As[0][0];   // [4 wc][256 rows]
  float* redC = redR + 1024;         // [2 wr][256 cols]

  float colAcc[4] = {0.f, 0.f, 0.f, 0.f};
  #pragma unroll
  for (int mi = 0; mi < 8; ++mi) {
    #pragma unroll
    for (int r = 0; r < 4; ++r) {
      const int ig = i0 + wrow + mi * 16 + q * 4 + r;
      float s = 0.f;
      #pragma unroll
      for (int ni = 0; ni < 4; ++ni) {
        const float v = __expf(acc[mi][ni][r] * INV_TEMP);
        s += v;
        colAcc[ni] += v;
        const int jg = j0 + wcol + ni * 16 + m;
        if (((ig ^ jg) & (NB - 1)) == 0) {
          diag[(((ig >> 11) << 2) + (jg >> 11)) * NB + (ig & (NB - 1))] = v;
        }
      }
      s += __shfl_xor(s, 1);
      s += __shfl_xor(s, 2);
      s += __shfl_xor(s, 4);
      s += __shfl_xor(s, 8);
      if (m == 0) redR[wc * 256 + wrow + mi * 16 + q * 4 + r] = s;
    }
  }
  #pragma unroll
  for (int ni = 0; ni < 4; ++ni) {
    float c = colAcc[ni];
    c += __shfl_xor(c, 16);
    c += __shfl_xor(c, 32);
    if (q == 0) redC[wr * 256 + wcol + ni * 16 + m] = c;
  }
  __syncthreads();
  if (tid < 256) {
    const float rs = redR[tid] + redR[256 + tid] + redR[512 + tid] + redR[768 + tid];
    rsp[(size_t)bx * 4096 + i0 + tid] = rs;
    if (sym) {
      const float cs = redC[tid] + redC[256 + tid];
      rsp[(size_t)by * 4096 + j0 + tid] = cs;
    }
  }
}

// ---------------------------------------------------------------------------
// Kernel 3: per-row losses (32 slots/row; diag mirror for k.e) + final scalars
// (merged former k_rowloss + k_out: one 1024-thread block, 2 rows/thread)
// ---------------------------------------------------------------------------
__global__ __launch_bounds__(1024) void k_final(
    const float* __restrict__ rsp, const float* __restrict__ diag,
    const float* __restrict__ reg_partial, float* __restrict__ out)
{
  const int tid = threadIdx.x;
  const int wave = tid >> 6, lane = tid & 63;
  float l = 0.f, g = 0.f;
  #pragma unroll
  for (int h = 0; h < 2; ++h) {
    const int n = tid + h * 1024;   // 0..2047
    float se = 0.f, sk = 0.f;
    #pragma unroll 8
    for (int s = 0; s < 32; ++s) {
      se += rsp[s * 4096 + n];
      sk += rsp[s * 4096 + 2048 + n];
    }
    const float d_ee  = diag[0 * NB + n];
    const float d_ek  = diag[1 * NB + n];
    const float d_eet = diag[2 * NB + n];
    const float d_ekt = diag[3 * NB + n];
    const float d_kk  = diag[5 * NB + n];
    const float d_ket = diag[6 * NB + n];
    const float d_kkt = diag[7 * NB + n];
    const float num_e = d_ek + d_eet + d_ekt;
    const float num_k = d_ek + d_ket + d_kkt;   // k.e diag == e.k diag (mirror)
    l += logf((se - d_ee) / num_e) + logf((sk - d_kk) / num_k);
    g += reg_partial[n];
  }
  #pragma unroll
  for (int o = 1; o < 64; o <<= 1) { l += __shfl_xor(l, o); g += __shfl_xor(g, o); }
  __shared__ float rl[16], rg[16];
  if (lane == 0) { rl[wave] = l; rg[wave] = g; }
  __syncthreads();
  if (tid == 0) {
    float L = 0.f, G = 0.f;
    #pragma unroll
    for (int i = 0; i < 16; ++i) { L += rl[i]; G += rg[i]; }
    const float contrastive = L * (1.0f / (2.0f * NB));
    const float cs = G * (1.0f / NB);
    out[0] = contrastive + LAMBDA_CS * cs;
    out[1] = contrastive;
    out[2] = cs;
  }
}

// ---------------------------------------------------------------------------
extern "C" void kernel_launch(void* const* d_in, const int* in_sizes, int n_in,
                              void* d_out, int out_size, void* d_ws, size_t ws_size,
                              hipStream_t stream) {
  const float* english = (const float*)d_in[0];
  const float* etok    = (const float*)d_in[1];
  const float* ktoe    = (const float*)d_in[2];
  const float* korean  = (const float*)d_in[3];
  const float* ratios  = (const float*)d_in[4];

  char* ws = (char*)d_ws;
  const size_t OFF_M    = 0;                                   // 16777216 B
  const size_t OFF_RSP  = OFF_M + (size_t)8192 * 1024 * 2;     // 32*4096*4 = 512 KB
  const size_t OFF_DIAG = OFF_RSP + (size_t)32 * 4096 * 4;     // 8*2048*4
  const size_t OFF_REG  = OFF_DIAG + 8 * NB * sizeof(float);   // 2048*4

  ushort* M           = (ushort*)(ws + OFF_M);
  float* rsp          = (float*)(ws + OFF_RSP);
  float* diag         = (float*)(ws + OFF_DIAG);
  float* reg_partial  = (float*)(ws + OFF_REG);

  k_norm_reg<<<dim3(NB), 256, 0, stream>>>(english, korean, etok, ktoe, ratios, M, reg_partial);
  k_gemm_exp_rowsum<<<dim3(392), 512, 0, stream>>>(M, rsp, diag);
  k_final<<<dim3(1), 1024, 0, stream>>>(rsp, diag, reg_partial, (float*)d_out);
}

// Round 2
// 169.726 us; speedup vs baseline: 1.0127x; 1.0127x over previous
//
#include <hip/hip_runtime.h>
#include <math.h>

// Problem constants
#define NB   2048     // batch
#define ND   1024     // dim
#define INV_TEMP 10.0f
#define LAMBDA_CS 0.5f

using short8  = __attribute__((ext_vector_type(8))) short;
using floatx4 = __attribute__((ext_vector_type(4))) float;

__device__ __forceinline__ ushort f32_to_bf16_rne(float f) {
  union { float f; unsigned u; } v; v.f = f;
  unsigned u = v.u;
  u += 0x7FFFu + ((u >> 16) & 1u);   // round-to-nearest-even
  return (ushort)(u >> 16);
}

// ---------------------------------------------------------------------------
// Kernel 1: fused row L2-normalize (-> bf16 M, t-order {e,k,et,kt}) + cs-reg
// partial per row + rowsum zero-init. One block per row b.
// ---------------------------------------------------------------------------
__global__ __launch_bounds__(256) void k_norm_reg(
    const float* __restrict__ e, const float* __restrict__ k,
    const float* __restrict__ et, const float* __restrict__ kt,
    const float* __restrict__ ratios,
    ushort* __restrict__ M, float* __restrict__ reg_partial,
    float* __restrict__ rowsum)
{
  const int b = blockIdx.x, tid = threadIdx.x;
  const int wave = tid >> 6, lane = tid & 63;

  float4 ve  = ((const float4*)(e  + (size_t)b * ND))[tid];
  float4 vk  = ((const float4*)(k  + (size_t)b * ND))[tid];
  float4 vet = ((const float4*)(et + (size_t)b * ND))[tid];
  float4 vkt = ((const float4*)(kt + (size_t)b * ND))[tid];

  float s0 = ve.x*ve.x + ve.y*ve.y + ve.z*ve.z + ve.w*ve.w;
  float s1 = vk.x*vk.x + vk.y*vk.y + vk.z*vk.z + vk.w*vk.w;
  float s2 = vet.x*vet.x + vet.y*vet.y + vet.z*vet.z + vet.w*vet.w;
  float s3 = vkt.x*vkt.x + vkt.y*vkt.y + vkt.z*vkt.z + vkt.w*vkt.w;
  #pragma unroll
  for (int o = 1; o < 64; o <<= 1) {
    s0 += __shfl_xor(s0, o); s1 += __shfl_xor(s1, o);
    s2 += __shfl_xor(s2, o); s3 += __shfl_xor(s3, o);
  }
  __shared__ float red[4][4];
  if (lane == 0) { red[wave][0] = s0; red[wave][1] = s1; red[wave][2] = s2; red[wave][3] = s3; }
  __syncthreads();
  const float ie  = 1.0f / sqrtf(red[0][0] + red[1][0] + red[2][0] + red[3][0]);
  const float ik  = 1.0f / sqrtf(red[0][1] + red[1][1] + red[2][1] + red[3][1]);
  const float iet = 1.0f / sqrtf(red[0][2] + red[1][2] + red[2][2] + red[3][2]);
  const float ikt = 1.0f / sqrtf(red[0][3] + red[1][3] + red[2][3] + red[3][3]);

  // write normalized bf16 rows, t order {0:e, 1:k, 2:et, 3:kt}
  {
    ushort o4[4];
    o4[0] = f32_to_bf16_rne(ve.x * ie);  o4[1] = f32_to_bf16_rne(ve.y * ie);
    o4[2] = f32_to_bf16_rne(ve.z * ie);  o4[3] = f32_to_bf16_rne(ve.w * ie);
    *(ushort4*)(M + ((size_t)0 * NB + b) * ND + tid * 4) = *(ushort4*)o4;
    o4[0] = f32_to_bf16_rne(vk.x * ik);  o4[1] = f32_to_bf16_rne(vk.y * ik);
    o4[2] = f32_to_bf16_rne(vk.z * ik);  o4[3] = f32_to_bf16_rne(vk.w * ik);
    *(ushort4*)(M + ((size_t)1 * NB + b) * ND + tid * 4) = *(ushort4*)o4;
    o4[0] = f32_to_bf16_rne(vet.x * iet); o4[1] = f32_to_bf16_rne(vet.y * iet);
    o4[2] = f32_to_bf16_rne(vet.z * iet); o4[3] = f32_to_bf16_rne(vet.w * iet);
    *(ushort4*)(M + ((size_t)2 * NB + b) * ND + tid * 4) = *(ushort4*)o4;
    o4[0] = f32_to_bf16_rne(vkt.x * ikt); o4[1] = f32_to_bf16_rne(vkt.y * ikt);
    o4[2] = f32_to_bf16_rne(vkt.z * ikt); o4[3] = f32_to_bf16_rne(vkt.w * ikt);
    *(ushort4*)(M + ((size_t)3 * NB + b) * ND + tid * 4) = *(ushort4*)o4;
  }

  // cs-reg partial
  const float r = ratios[b], rm = 1.0f - r;
  float a1 = 0.f, a2 = 0.f;
  {
    float en, kn, d1, d2;
    en = ve.x*ie; kn = vk.x*ik;
    d1 = vet.x*iet - (r*en + rm*kn); d2 = vkt.x*ikt - (rm*en + r*kn);
    a1 += d1*d1; a2 += d2*d2;
    en = ve.y*ie; kn = vk.y*ik;
    d1 = vet.y*iet - (r*en + rm*kn); d2 = vkt.y*ikt - (rm*en + r*kn);
    a1 += d1*d1; a2 += d2*d2;
    en = ve.z*ie; kn = vk.z*ik;
    d1 = vet.z*iet - (r*en + rm*kn); d2 = vkt.z*ikt - (rm*en + r*kn);
    a1 += d1*d1; a2 += d2*d2;
    en = ve.w*ie; kn = vk.w*ik;
    d1 = vet.w*iet - (r*en + rm*kn); d2 = vkt.w*ikt - (rm*en + r*kn);
    a1 += d1*d1; a2 += d2*d2;
  }
  #pragma unroll
  for (int o = 1; o < 64; o <<= 1) { a1 += __shfl_xor(a1, o); a2 += __shfl_xor(a2, o); }
  __shared__ float red2[4][2];
  if (lane == 0) { red2[wave][0] = a1; red2[wave][1] = a2; }
  __syncthreads();
  if (tid == 0) {
    float t1 = red2[0][0] + red2[1][0] + red2[2][0] + red2[3][0];
    float t2 = red2[0][1] + red2[1][1] + red2[2][1] + red2[3][1];
    reg_partial[b] = sqrtf(t1) + sqrtf(t2);
    rowsum[b] = 0.f;            // zero-init for gemm's atomics
    rowsum[NB + b] = 0.f;
  }
}

// ---------------------------------------------------------------------------
// Kernel 2: 256x256-tile, BK=64, 8-wave, 8-phase counted-vmcnt GEMM
// (T2 swizzle + T3/T4 schedule + T5 setprio + T1 XCD swizzle), fused exp +
// atomic row-sum accumulation + diagonal capture + symmetric column-sum
// mirror. Grid: 392 = 256 (right half) + 136 (upper triangle of symmetric
// left half). 392 = 8*49 -> bijective XCD swizzle.
// Stage-first phases: global_load_lds issued before the phase's ds_reads.
// vmcnt(4) only at phases 4/8 (2 half-tiles in flight across barriers).
// ---------------------------------------------------------------------------

#define STAGE_A(TT, HH, BUF) do {                                              \
  _Pragma("unroll")                                                            \
  for (int L_ = 0; L_ < 2; ++L_) {                                             \
    const int u_ = L_ * 512 + tid;                                             \
    const int rr_ = u_ >> 3;                                                   \
    const int sc_ = ((u_ & 7) * 16) ^ ((rr_ & 7) << 4);                        \
    const ushort* gp_ = M + (size_t)(i0 + (HH)*128 + rr_) * ND + (TT)*64 + (sc_ >> 1); \
    __builtin_amdgcn_global_load_lds(                                          \
        (const __attribute__((address_space(1))) unsigned int*)gp_,            \
        (__attribute__((address_space(3))) unsigned int*)&As[BUF][(HH)*8192 + L_*4096 + wave*512], \
        16, 0, 0);                                                             \
  }                                                                            \
} while (0)

#define STAGE_B(TT, HH, BUF) do {                                              \
  _Pragma("unroll")                                                            \
  for (int L_ = 0; L_ < 2; ++L_) {                                             \
    const int u_ = L_ * 512 + tid;                                             \
    const int rr_ = u_ >> 3;                                                   \
    const int sc_ = ((u_ & 7) * 16) ^ ((rr_ & 7) << 4);                        \
    const ushort* gp_ = M + (size_t)(j0 + (HH)*128 + rr_) * ND + (TT)*64 + (sc_ >> 1); \
    __builtin_amdgcn_global_load_lds(                                          \
        (const __attribute__((address_space(1))) unsigned int*)gp_,            \
        (__attribute__((address_space(3))) unsigned int*)&Bs[BUF][(HH)*8192 + L_*4096 + wave*512], \
        16, 0, 0);                                                             \
  }                                                                            \
} while (0)

#define PHASE(BUF, MQ, KK, LOADB, WAIT, STMT) do {                             \
  STMT;                                                                        \
  short8 af_[4];                                                               \
  _Pragma("unroll")                                                            \
  for (int mi_ = 0; mi_ < 4; ++mi_) {                                          \
    const int row_ = wrow + ((MQ)*4 + mi_)*16 + m;                             \
    const int cb_ = ((KK)*64 + q*16) ^ ((row_ & 7) << 4);                      \
    af_[mi_] = *(const short8*)&As[BUF][row_*64 + (cb_ >> 1)];                 \
  }                                                                            \
  if (LOADB) {                                                                 \
    _Pragma("unroll")                                                          \
    for (int ni_ = 0; ni_ < 4; ++ni_) {                                        \
      const int rb_ = wcol + ni_*16 + m;                                       \
      const int cb_ = ((KK)*64 + q*16) ^ ((rb_ & 7) << 4);                     \
      bfr[KK][ni_] = *(const short8*)&Bs[BUF][rb_*64 + (cb_ >> 1)];            \
    }                                                                          \
  }                                                                            \
  __builtin_amdgcn_s_barrier();                                                \
  asm volatile("s_waitcnt lgkmcnt(0)" ::: "memory");                           \
  __builtin_amdgcn_s_setprio(1);                                               \
  _Pragma("unroll")                                                            \
  for (int mi_ = 0; mi_ < 4; ++mi_)                                            \
    _Pragma("unroll")                                                          \
    for (int ni_ = 0; ni_ < 4; ++ni_)                                          \
      acc[(MQ)*4 + mi_][ni_] = __builtin_amdgcn_mfma_f32_16x16x32_bf16(        \
          af_[mi_], bfr[KK][ni_], acc[(MQ)*4 + mi_][ni_], 0, 0, 0);            \
  __builtin_amdgcn_s_setprio(0);                                               \
  if (WAIT) asm volatile("s_waitcnt vmcnt(4)" ::: "memory");                   \
  __builtin_amdgcn_s_barrier();                                                \
} while (0)

__global__ __launch_bounds__(512, 2) void k_gemm_exp_rowsum(
    const ushort* __restrict__ M,
    float* __restrict__ rowsum,   // [4096] atomic accumulators
    float* __restrict__ diag)     // [2][4][2048]  (side, t, n); slot 4 unused
{
  __shared__ __align__(16) ushort As[2][16384];
  __shared__ __align__(16) ushort Bs[2][16384];

  int bx, by;
  {
    // T1: bijective XCD swizzle (392 = 8 * 49)
    int idx = (blockIdx.x & 7) * 49 + (blockIdx.x >> 3);
    if (idx < 256) { by = idx >> 4; bx = 16 + (idx & 15); }
    else {
      int t = idx - 256; by = 0;
      while (t >= 16 - by) { t -= 16 - by; ++by; }
      bx = by + t;
    }
  }
  const bool sym = (bx < 16) && (bx > by);
  const int i0 = by * 256;
  const int j0 = bx * 256;

  const int tid  = threadIdx.x;
  const int wave = tid >> 6;
  const int lane = tid & 63;
  const int q = lane >> 4;       // quad 0..3
  const int m = lane & 15;       // spatial index within 16
  const int wr = wave >> 2;      // 0..1
  const int wc = wave & 3;       // 0..3
  const int wrow = wr * 128;
  const int wcol = wc * 64;

  floatx4 acc[8][4] = {};
  short8 bfr[2][4];

  // prologue: A(0), B(0), B(1); leave B(1) (4 loads) in flight
  STAGE_A(0, 0, 0); STAGE_A(0, 1, 0);
  STAGE_B(0, 0, 0); STAGE_B(0, 1, 0);
  STAGE_B(1, 0, 1); STAGE_B(1, 1, 1);
  asm volatile("s_waitcnt vmcnt(4)" ::: "memory");
  __builtin_amdgcn_s_barrier();

  #pragma unroll 1
  for (int i = 0; i < 8; ++i) {
    const int t1 = 2*i + 1;
    const int t2 = (2*i + 2) & 15;   // last iter wraps: harmless re-fetch,
    const int t3 = (2*i + 3) & 15;   // drained by __syncthreads below
    PHASE(0, 0, 0, 1, 0, STAGE_A(t1, 0, 1));
    PHASE(0, 0, 1, 1, 0, STAGE_A(t1, 1, 1));
    PHASE(0, 1, 0, 0, 0, STAGE_B(t2, 0, 0));
    PHASE(0, 1, 1, 0, 1, STAGE_B(t2, 1, 0));
    PHASE(1, 0, 0, 1, 0, STAGE_A(t2, 0, 0));
    PHASE(1, 0, 1, 1, 0, STAGE_A(t2, 1, 0));
    PHASE(1, 1, 0, 0, 0, STAGE_B(t3, 0, 1));
    PHASE(1, 1, 1, 0, 1, STAGE_B(t3, 1, 1));
  }

  __syncthreads();   // full vmcnt/lgkmcnt drain + barrier before LDS overlay

  // Epilogue. C/D layout: col = lane&15, row = q*4 + reg  [m89/m91]
  float* redR = (float*)&As[0][0];   // [4 wc][256 rows]
  float* redC = redR + 1024;         // [2 wr][256 cols]

  float colAcc[4] = {0.f, 0.f, 0.f, 0.f};
  #pragma unroll
  for (int mi = 0; mi < 8; ++mi) {
    #pragma unroll
    for (int r = 0; r < 4; ++r) {
      const int ig = i0 + wrow + mi * 16 + q * 4 + r;
      float s = 0.f;
      #pragma unroll
      for (int ni = 0; ni < 4; ++ni) {
        const float v = __expf(acc[mi][ni][r] * INV_TEMP);
        s += v;
        colAcc[ni] += v;
        const int jg = j0 + wcol + ni * 16 + m;
        if (((ig ^ jg) & (NB - 1)) == 0) {
          diag[(((ig >> 11) << 2) + (jg >> 11)) * NB + (ig & (NB - 1))] = v;
        }
      }
      s += __shfl_xor(s, 1);
      s += __shfl_xor(s, 2);
      s += __shfl_xor(s, 4);
      s += __shfl_xor(s, 8);
      if (m == 0) redR[wc * 256 + wrow + mi * 16 + q * 4 + r] = s;
    }
  }
  #pragma unroll
  for (int ni = 0; ni < 4; ++ni) {
    float c = colAcc[ni];
    c += __shfl_xor(c, 16);
    c += __shfl_xor(c, 32);
    if (q == 0) redC[wr * 256 + wcol + ni * 16 + m] = c;
  }
  __syncthreads();
  if (tid < 256) {
    const float rs = redR[tid] + redR[256 + tid] + redR[512 + tid] + redR[768 + tid];
    atomicAdd(&rowsum[i0 + tid], rs);
    if (sym) {
      const float cs = redC[tid] + redC[256 + tid];
      atomicAdd(&rowsum[j0 + tid], cs);
    }
  }
}

// ---------------------------------------------------------------------------
// Kernel 3: per-row losses (rowsum direct; diag mirror for k.e) + final
// scalars. One 1024-thread block, 2 rows/thread.
// ---------------------------------------------------------------------------
__global__ __launch_bounds__(1024) void k_final(
    const float* __restrict__ rowsum, const float* __restrict__ diag,
    const float* __restrict__ reg_partial, float* __restrict__ out)
{
  const int tid = threadIdx.x;
  const int wave = tid >> 6, lane = tid & 63;
  float l = 0.f, g = 0.f;
  #pragma unroll
  for (int h = 0; h < 2; ++h) {
    const int n = tid + h * 1024;   // 0..2047
    const float se = rowsum[n];
    const float sk = rowsum[NB + n];
    const float d_ee  = diag[0 * NB + n];
    const float d_ek  = diag[1 * NB + n];
    const float d_eet = diag[2 * NB + n];
    const float d_ekt = diag[3 * NB + n];
    const float d_kk  = diag[5 * NB + n];
    const float d_ket = diag[6 * NB + n];
    const float d_kkt = diag[7 * NB + n];
    const float num_e = d_ek + d_eet + d_ekt;
    const float num_k = d_ek + d_ket + d_kkt;   // k.e diag == e.k diag (mirror)
    l += logf((se - d_ee) / num_e) + logf((sk - d_kk) / num_k);
    g += reg_partial[n];
  }
  #pragma unroll
  for (int o = 1; o < 64; o <<= 1) { l += __shfl_xor(l, o); g += __shfl_xor(g, o); }
  __shared__ float rl[16], rg[16];
  if (lane == 0) { rl[wave] = l; rg[wave] = g; }
  __syncthreads();
  if (tid == 0) {
    float L = 0.f, G = 0.f;
    #pragma unroll
    for (int i = 0; i < 16; ++i) { L += rl[i]; G += rg[i]; }
    const float contrastive = L * (1.0f / (2.0f * NB));
    const float cs = G * (1.0f / NB);
    out[0] = contrastive + LAMBDA_CS * cs;
    out[1] = contrastive;
    out[2] = cs;
  }
}

// ---------------------------------------------------------------------------
extern "C" void kernel_launch(void* const* d_in, const int* in_sizes, int n_in,
                              void* d_out, int out_size, void* d_ws, size_t ws_size,
                              hipStream_t stream) {
  const float* english = (const float*)d_in[0];
  const float* etok    = (const float*)d_in[1];
  const float* ktoe    = (const float*)d_in[2];
  const float* korean  = (const float*)d_in[3];
  const float* ratios  = (const float*)d_in[4];

  char* ws = (char*)d_ws;
  const size_t OFF_M    = 0;                                   // 16777216 B
  const size_t OFF_ROW  = OFF_M + (size_t)8192 * 1024 * 2;     // 4096*4
  const size_t OFF_DIAG = OFF_ROW + (size_t)4096 * 4;          // 8*2048*4
  const size_t OFF_REG  = OFF_DIAG + 8 * NB * sizeof(float);   // 2048*4

  ushort* M           = (ushort*)(ws + OFF_M);
  float* rowsum       = (float*)(ws + OFF_ROW);
  float* diag         = (float*)(ws + OFF_DIAG);
  float* reg_partial  = (float*)(ws + OFF_REG);

  k_norm_reg<<<dim3(NB), 256, 0, stream>>>(english, korean, etok, ktoe, ratios, M, reg_partial, rowsum);
  k_gemm_exp_rowsum<<<dim3(392), 512, 0, stream>>>(M, rowsum, diag);
  k_final<<<dim3(1), 1024, 0, stream>>>(rowsum, diag, reg_partial, (float*)d_out);
}

// Round 3
// 168.104 us; speedup vs baseline: 1.0225x; 1.0097x over previous
//
#include <hip/hip_runtime.h>
#include <math.h>

// Problem constants
#define NB   2048     // batch
#define ND   1024     // dim
#define INV_TEMP 10.0f
#define LAMBDA_CS 0.5f

using short8  = __attribute__((ext_vector_type(8))) short;
using floatx4 = __attribute__((ext_vector_type(4))) float;

__device__ __forceinline__ ushort f32_to_bf16_rne(float f) {
  union { float f; unsigned u; } v; v.f = f;
  unsigned u = v.u;
  u += 0x7FFFu + ((u >> 16) & 1u);   // round-to-nearest-even
  return (ushort)(u >> 16);
}

// ---------------------------------------------------------------------------
// Kernel 1: fused row L2-normalize (-> bf16 M, t-order {e,k,et,kt}) + cs-reg
// partial per row + rowsum zero-init. One block per row b.
// ---------------------------------------------------------------------------
__global__ __launch_bounds__(256) void k_norm_reg(
    const float* __restrict__ e, const float* __restrict__ k,
    const float* __restrict__ et, const float* __restrict__ kt,
    const float* __restrict__ ratios,
    ushort* __restrict__ M, float* __restrict__ reg_partial,
    float* __restrict__ rowsum)
{
  const int b = blockIdx.x, tid = threadIdx.x;
  const int wave = tid >> 6, lane = tid & 63;

  float4 ve  = ((const float4*)(e  + (size_t)b * ND))[tid];
  float4 vk  = ((const float4*)(k  + (size_t)b * ND))[tid];
  float4 vet = ((const float4*)(et + (size_t)b * ND))[tid];
  float4 vkt = ((const float4*)(kt + (size_t)b * ND))[tid];

  float s0 = ve.x*ve.x + ve.y*ve.y + ve.z*ve.z + ve.w*ve.w;
  float s1 = vk.x*vk.x + vk.y*vk.y + vk.z*vk.z + vk.w*vk.w;
  float s2 = vet.x*vet.x + vet.y*vet.y + vet.z*vet.z + vet.w*vet.w;
  float s3 = vkt.x*vkt.x + vkt.y*vkt.y + vkt.z*vkt.z + vkt.w*vkt.w;
  #pragma unroll
  for (int o = 1; o < 64; o <<= 1) {
    s0 += __shfl_xor(s0, o); s1 += __shfl_xor(s1, o);
    s2 += __shfl_xor(s2, o); s3 += __shfl_xor(s3, o);
  }
  __shared__ float red[4][4];
  if (lane == 0) { red[wave][0] = s0; red[wave][1] = s1; red[wave][2] = s2; red[wave][3] = s3; }
  __syncthreads();
  const float ie  = 1.0f / sqrtf(red[0][0] + red[1][0] + red[2][0] + red[3][0]);
  const float ik  = 1.0f / sqrtf(red[0][1] + red[1][1] + red[2][1] + red[3][1]);
  const float iet = 1.0f / sqrtf(red[0][2] + red[1][2] + red[2][2] + red[3][2]);
  const float ikt = 1.0f / sqrtf(red[0][3] + red[1][3] + red[2][3] + red[3][3]);

  // write normalized bf16 rows, t order {0:e, 1:k, 2:et, 3:kt}
  {
    ushort o4[4];
    o4[0] = f32_to_bf16_rne(ve.x * ie);  o4[1] = f32_to_bf16_rne(ve.y * ie);
    o4[2] = f32_to_bf16_rne(ve.z * ie);  o4[3] = f32_to_bf16_rne(ve.w * ie);
    *(ushort4*)(M + ((size_t)0 * NB + b) * ND + tid * 4) = *(ushort4*)o4;
    o4[0] = f32_to_bf16_rne(vk.x * ik);  o4[1] = f32_to_bf16_rne(vk.y * ik);
    o4[2] = f32_to_bf16_rne(vk.z * ik);  o4[3] = f32_to_bf16_rne(vk.w * ik);
    *(ushort4*)(M + ((size_t)1 * NB + b) * ND + tid * 4) = *(ushort4*)o4;
    o4[0] = f32_to_bf16_rne(vet.x * iet); o4[1] = f32_to_bf16_rne(vet.y * iet);
    o4[2] = f32_to_bf16_rne(vet.z * iet); o4[3] = f32_to_bf16_rne(vet.w * iet);
    *(ushort4*)(M + ((size_t)2 * NB + b) * ND + tid * 4) = *(ushort4*)o4;
    o4[0] = f32_to_bf16_rne(vkt.x * ikt); o4[1] = f32_to_bf16_rne(vkt.y * ikt);
    o4[2] = f32_to_bf16_rne(vkt.z * ikt); o4[3] = f32_to_bf16_rne(vkt.w * ikt);
    *(ushort4*)(M + ((size_t)3 * NB + b) * ND + tid * 4) = *(ushort4*)o4;
  }

  // cs-reg partial
  const float r = ratios[b], rm = 1.0f - r;
  float a1 = 0.f, a2 = 0.f;
  {
    float en, kn, d1, d2;
    en = ve.x*ie; kn = vk.x*ik;
    d1 = vet.x*iet - (r*en + rm*kn); d2 = vkt.x*ikt - (rm*en + r*kn);
    a1 += d1*d1; a2 += d2*d2;
    en = ve.y*ie; kn = vk.y*ik;
    d1 = vet.y*iet - (r*en + rm*kn); d2 = vkt.y*ikt - (rm*en + r*kn);
    a1 += d1*d1; a2 += d2*d2;
    en = ve.z*ie; kn = vk.z*ik;
    d1 = vet.z*iet - (r*en + rm*kn); d2 = vkt.z*ikt - (rm*en + r*kn);
    a1 += d1*d1; a2 += d2*d2;
    en = ve.w*ie; kn = vk.w*ik;
    d1 = vet.w*iet - (r*en + rm*kn); d2 = vkt.w*ikt - (rm*en + r*kn);
    a1 += d1*d1; a2 += d2*d2;
  }
  #pragma unroll
  for (int o = 1; o < 64; o <<= 1) { a1 += __shfl_xor(a1, o); a2 += __shfl_xor(a2, o); }
  __shared__ float red2[4][2];
  if (lane == 0) { red2[wave][0] = a1; red2[wave][1] = a2; }
  __syncthreads();
  if (tid == 0) {
    float t1 = red2[0][0] + red2[1][0] + red2[2][0] + red2[3][0];
    float t2 = red2[0][1] + red2[1][1] + red2[2][1] + red2[3][1];
    reg_partial[b] = sqrtf(t1) + sqrtf(t2);
    rowsum[b] = 0.f;            // zero-init for gemm's atomics
    rowsum[NB + b] = 0.f;
  }
}

// ---------------------------------------------------------------------------
// Kernel 2: 128x128-tile, BK=32, 4-wave, 3-LDS-buffer counted-vmcnt GEMM
// + fused exp + atomic row-sum + diagonal capture + symmetric col-sum mirror.
//   Grid: 1552 = 1024 (right half, bx in [32,64)) + 528 (upper-tri incl
//   diagonal of left half, bx in [by,32)). 48 KB LDS, ~3 blocks/CU:
//   co-resident blocks mutually hide barrier/load stalls (m114 mechanism).
//   Pipeline: during tile t, stage tile t+2 into buf[(t+2)%3] (= buffer last
//   read at t-1; safe after the end-of-(t-1) barrier). Per K-step: one raw
//   s_barrier + lgkmcnt(0) before MFMA + counted vmcnt(4) (retires t+1's 4
//   loads, leaves t+2's in flight) -- never drains to 0 in the loop (T4).
//   Tail wraps (t+2)&31: harmless refetch, drained by final __syncthreads.
// ---------------------------------------------------------------------------

#define GLDS(GP, LP)                                                           \
  __builtin_amdgcn_global_load_lds(                                            \
      (const __attribute__((address_space(1))) unsigned int*)(GP),             \
      (__attribute__((address_space(3))) unsigned int*)(LP), 16, 0, 0)

// stage tile TT (K-offset TT*32) into buffer BUF; 4 gloads per wave
#define STAGE(TT, BUF) do {                                                    \
  GLDS(gA + (size_t)(c0 * 16 + srow) * ND + (TT) * 32 + scol * 8,              \
       &As[BUF][c0 * 512]);                                                    \
  GLDS(gA + (size_t)(c1 * 16 + srow) * ND + (TT) * 32 + scol * 8,              \
       &As[BUF][c1 * 512]);                                                    \
  GLDS(gB + (size_t)(c0 * 16 + srow) * ND + (TT) * 32 + scol * 8,              \
       &Bs[BUF][c0 * 512]);                                                    \
  GLDS(gB + (size_t)(c1 * 16 + srow) * ND + (TT) * 32 + scol * 8,              \
       &Bs[BUF][c1 * 512]);                                                    \
} while (0)

__global__ __launch_bounds__(256, 3) void k_gemm_exp_rowsum(
    const ushort* __restrict__ M,
    float* __restrict__ rowsum,   // [4096] atomic accumulators
    float* __restrict__ diag)     // [2][4][2048]  (side, t, n); slot 4 unused
{
  __shared__ __align__(16) ushort As[3][4096];   // 3 x 8KB
  __shared__ __align__(16) ushort Bs[3][4096];   // 3 x 8KB
  __shared__ float redR[256];
  __shared__ float redC[256];

  // decode (bx, by) from linear block id
  int bx, by;
  {
    int idx = blockIdx.x;
    if (idx < 1024) { by = idx >> 5; bx = 32 + (idx & 31); }
    else {
      int t = idx - 1024; by = 0;
      while (t >= 32 - by) { t -= 32 - by; ++by; }
      bx = by + t;
    }
  }
  const bool sym = (bx < 32) && (bx > by);
  const int j0 = bx * 128;
  const int i0 = by * 128;

  const int tid  = threadIdx.x;
  const int wave = tid >> 6;
  const int lane = tid & 63;
  const int q = lane >> 4;       // quad 0..3
  const int m = lane & 15;       // spatial index within 16
  const int wrow = (wave >> 1) * 64;
  const int wcol = (wave & 1) * 64;

  floatx4 acc[4][4] = {};

  // staging geometry: chunk = 16 rows x 32 K-cols (1 KB); XOR col swizzle
  const int srow = lane >> 2;
  const int scol = (lane & 3) ^ ((srow >> 1) & 3);
  const int c0 = wave * 2, c1 = c0 + 1;

  const ushort* gA = M + (size_t)i0 * ND;
  const ushort* gB = M + (size_t)j0 * ND;

  int aoff[4], boff[4];
  #pragma unroll
  for (int x = 0; x < 4; ++x) {
    const int sw = (q ^ ((m >> 1) & 3)) * 8;
    aoff[x] = (wrow + x * 16 + m) * 32 + sw;
    boff[x] = (wcol + x * 16 + m) * 32 + sw;
  }

  // prologue: tiles 0 and 1; wait tile0's 4 loads (leave tile1's in flight)
  STAGE(0, 0);
  STAGE(1, 1);
  asm volatile("s_waitcnt vmcnt(4)" ::: "memory");
  __builtin_amdgcn_s_barrier();

  int bcur = 0, bnext = 1, bstage = 2;
  #pragma unroll 1
  for (int t = 0; t < 32; ++t) {
    // stage tile t+2 into the buffer last read at t-1
    STAGE((t + 2) & 31, bstage);

    short8 af[4], bf[4];
    #pragma unroll
    for (int x = 0; x < 4; ++x) {
      af[x] = *(const short8*)&As[bcur][aoff[x]];
      bf[x] = *(const short8*)&Bs[bcur][boff[x]];
    }
    asm volatile("s_waitcnt lgkmcnt(0)" ::: "memory");
    __builtin_amdgcn_sched_barrier(0);      // rule #18: keep MFMA below the wait

    __builtin_amdgcn_s_setprio(1);
    #pragma unroll
    for (int mi = 0; mi < 4; ++mi)
      #pragma unroll
      for (int ni = 0; ni < 4; ++ni)
        acc[mi][ni] = __builtin_amdgcn_mfma_f32_16x16x32_bf16(
            af[mi], bf[ni], acc[mi][ni], 0, 0, 0);
    __builtin_amdgcn_s_setprio(0);

    // retire tile t+1's loads; keep tile t+2's 4 in flight (counted, never 0)
    asm volatile("s_waitcnt vmcnt(4)" ::: "memory");
    __builtin_amdgcn_s_barrier();

    const int tmp = bcur; bcur = bnext; bnext = bstage; bstage = tmp;
  }

  __syncthreads();   // full drain (incl. wrap-around stages) before epilogue

  // Epilogue. C/D layout: col = lane&15, row = q*4 + reg  [m89/m91]
  float colAcc[4] = {0.f, 0.f, 0.f, 0.f};
  #pragma unroll
  for (int mi = 0; mi < 4; ++mi) {
    #pragma unroll
    for (int r = 0; r < 4; ++r) {
      const int ig = i0 + wrow + mi * 16 + q * 4 + r;
      float s = 0.f;
      #pragma unroll
      for (int ni = 0; ni < 4; ++ni) {
        const float v = __expf(acc[mi][ni][r] * INV_TEMP);
        s += v;
        colAcc[ni] += v;
        const int jg = j0 + wcol + ni * 16 + m;
        if (((ig ^ jg) & (NB - 1)) == 0) {
          diag[(((ig >> 11) << 2) + (jg >> 11)) * NB + (ig & (NB - 1))] = v;
        }
      }
      s += __shfl_xor(s, 1);
      s += __shfl_xor(s, 2);
      s += __shfl_xor(s, 4);
      s += __shfl_xor(s, 8);
      if (m == 0) redR[(wave & 1) * 128 + wrow + mi * 16 + q * 4 + r] = s;
    }
  }
  #pragma unroll
  for (int ni = 0; ni < 4; ++ni) {
    float c = colAcc[ni];
    c += __shfl_xor(c, 16);
    c += __shfl_xor(c, 32);
    if (q == 0) redC[(wave >> 1) * 128 + wcol + ni * 16 + m] = c;
  }
  __syncthreads();
  if (tid < 128) {
    atomicAdd(&rowsum[i0 + tid], redR[tid] + redR[128 + tid]);
    if (sym)
      atomicAdd(&rowsum[j0 + tid], redC[tid] + redC[128 + tid]);
  }
}

// ---------------------------------------------------------------------------
// Kernel 3: per-row losses (rowsum direct; diag mirror for k.e) + final
// scalars. One 1024-thread block, 2 rows/thread.
// ---------------------------------------------------------------------------
__global__ __launch_bounds__(1024) void k_final(
    const float* __restrict__ rowsum, const float* __restrict__ diag,
    const float* __restrict__ reg_partial, float* __restrict__ out)
{
  const int tid = threadIdx.x;
  const int wave = tid >> 6, lane = tid & 63;
  float l = 0.f, g = 0.f;
  #pragma unroll
  for (int h = 0; h < 2; ++h) {
    const int n = tid + h * 1024;   // 0..2047
    const float se = rowsum[n];
    const float sk = rowsum[NB + n];
    const float d_ee  = diag[0 * NB + n];
    const float d_ek  = diag[1 * NB + n];
    const float d_eet = diag[2 * NB + n];
    const float d_ekt = diag[3 * NB + n];
    const float d_kk  = diag[5 * NB + n];
    const float d_ket = diag[6 * NB + n];
    const float d_kkt = diag[7 * NB + n];
    const float num_e = d_ek + d_eet + d_ekt;
    const float num_k = d_ek + d_ket + d_kkt;   // k.e diag == e.k diag (mirror)
    l += logf((se - d_ee) / num_e) + logf((sk - d_kk) / num_k);
    g += reg_partial[n];
  }
  #pragma unroll
  for (int o = 1; o < 64; o <<= 1) { l += __shfl_xor(l, o); g += __shfl_xor(g, o); }
  __shared__ float rl[16], rg[16];
  if (lane == 0) { rl[wave] = l; rg[wave] = g; }
  __syncthreads();
  if (tid == 0) {
    float L = 0.f, G = 0.f;
    #pragma unroll
    for (int i = 0; i < 16; ++i) { L += rl[i]; G += rg[i]; }
    const float contrastive = L * (1.0f / (2.0f * NB));
    const float cs = G * (1.0f / NB);
    out[0] = contrastive + LAMBDA_CS * cs;
    out[1] = contrastive;
    out[2] = cs;
  }
}

// ---------------------------------------------------------------------------
extern "C" void kernel_launch(void* const* d_in, const int* in_sizes, int n_in,
                              void* d_out, int out_size, void* d_ws, size_t ws_size,
                              hipStream_t stream) {
  const float* english = (const float*)d_in[0];
  const float* etok    = (const float*)d_in[1];
  const float* ktoe    = (const float*)d_in[2];
  const float* korean  = (const float*)d_in[3];
  const float* ratios  = (const float*)d_in[4];

  char* ws = (char*)d_ws;
  const size_t OFF_M    = 0;                                   // 16777216 B
  const size_t OFF_ROW  = OFF_M + (size_t)8192 * 1024 * 2;     // 4096*4
  const size_t OFF_DIAG = OFF_ROW + (size_t)4096 * 4;          // 8*2048*4
  const size_t OFF_REG  = OFF_DIAG + 8 * NB * sizeof(float);   // 2048*4

  ushort* M           = (ushort*)(ws + OFF_M);
  float* rowsum       = (float*)(ws + OFF_ROW);
  float* diag         = (float*)(ws + OFF_DIAG);
  float* reg_partial  = (float*)(ws + OFF_REG);

  k_norm_reg<<<dim3(NB), 256, 0, stream>>>(english, korean, etok, ktoe, ratios, M, reg_partial, rowsum);
  k_gemm_exp_rowsum<<<dim3(1552), 256, 0, stream>>>(M, rowsum, diag);
  k_final<<<dim3(1), 1024, 0, stream>>>(rowsum, diag, reg_partial, (float*)d_out);
}